// Round 4
// baseline (254.909 us; speedup 1.0000x reference)
//
#include <hip/hip_runtime.h>
#include <hip/hip_bf16.h>
#include <stdint.h>
#include <cmath>

typedef unsigned short u16;
typedef __attribute__((ext_vector_type(8))) short bf16x8;   // 8 bf16 = 4 VGPRs (MFMA A/B frag)
typedef __attribute__((ext_vector_type(4))) float f32x4;    // MFMA C/D frag

#define DEVI static __device__ __forceinline__

constexpr int S_LEN = 2048;
constexpr int NHEAD = 16;
constexpr int HDIM  = 64;
constexpr int HID   = 1024;
constexpr int MROWS = 4 * 2048;   // B*S = 8192

// ---------- helpers ----------
DEVI u16 f2bf(float x) {                       // RNE fp32 -> bf16
  union { float f; uint32_t u; } a; a.f = x;
  uint32_t r = a.u + 0x7fffu + ((a.u >> 16) & 1u);
  return (u16)(r >> 16);
}

DEVI void gload16(const void* g, void* l) {    // 16B global -> LDS direct (wave-uniform lds base + lane*16)
  __builtin_amdgcn_global_load_lds((const __attribute__((address_space(1))) void*)g,
                                   (__attribute__((address_space(3))) void*)l, 16, 0, 0);
}

DEVI void waitvm0_barrier() {                  // 2-phase tile boundary: drain own VMEM, raw barrier
  asm volatile("s_waitcnt vmcnt(0)" ::: "memory");
  __builtin_amdgcn_s_barrier();
}

// ---------- fp32 -> bf16 convert ----------
__global__ void k_cvt(const float* __restrict__ src, u16* __restrict__ dst, int n4) {
  int stride = gridDim.x * blockDim.x;
  for (int i = blockIdx.x * blockDim.x + threadIdx.x; i < n4; i += stride) {
    float4 v = reinterpret_cast<const float4*>(src)[i];
    ushort4 o;
    o.x = f2bf(v.x); o.y = f2bf(v.y); o.z = f2bf(v.z); o.w = f2bf(v.w);
    reinterpret_cast<ushort4*>(dst)[i] = o;
  }
}

// all four 1024x1024 weights in one launch: Wq,Wk,Wv -> Wqkv (concat), Wo -> Wobf
__global__ void k_cvtw(const float* __restrict__ Wq, const float* __restrict__ Wk,
                       const float* __restrict__ Wv, const float* __restrict__ Wo,
                       u16* __restrict__ Wqkv, u16* __restrict__ Wobf) {
  constexpr int Q4 = (HID * HID) / 4;                 // float4s per matrix
  int i = blockIdx.x * blockDim.x + threadIdx.x;      // grid exactly covers 4*Q4
  int mat = i >> 18, loc = i & (Q4 - 1);              // Q4 = 2^18
  const float* src = (mat == 0) ? Wq : (mat == 1) ? Wk : (mat == 2) ? Wv : Wo;
  u16* dst = (mat < 3) ? (Wqkv + mat * HID * HID) : Wobf;
  float4 v = reinterpret_cast<const float4*>(src)[loc];
  ushort4 o;
  o.x = f2bf(v.x); o.y = f2bf(v.y); o.z = f2bf(v.z); o.w = f2bf(v.w);
  reinterpret_cast<ushort4*>(dst)[loc] = o;
}

// ---------- shared 128x128 B^T GEMM mainloop, 2-phase double-buffered ----------
// C[M,N] = A[M,K] * B[N,K]^T, K=1024, bf16 in, fp32 acc. 4 waves (2x2), BK=32.
// One barrier per K-step: STAGE(next) -> compute(cur) -> vmcnt(0)+s_barrier.
DEVI void gemm_ml(const u16* __restrict__ A, const u16* __restrict__ Bm,
                  int brow, int bcol, u16* As, u16* Bs, f32x4 acc[4][4]) {
  const int tid = threadIdx.x;
  const int wid = tid >> 6, lane = tid & 63;
  const int lr = lane & 15, lg = lane >> 4;
  const int wr = wid >> 1, wc = wid & 1;

#define GEMM_STAGE(KT, BUF)                                                              \
  _Pragma("unroll")                                                                      \
  for (int c = 0; c < 2; ++c) {                                                          \
    int e = c * 2048 + tid * 8;                                                          \
    int row = e >> 5, kk = e & 31;                                                       \
    gload16(A  + (size_t)(brow + row) * HID + (KT) * 32 + kk,                            \
            As + (BUF) * 4096 + c * 2048 + wid * 512);                                   \
    gload16(Bm + (size_t)(bcol + row) * HID + (KT) * 32 + kk,                            \
            Bs + (BUF) * 4096 + c * 2048 + wid * 512);                                   \
  }

  GEMM_STAGE(0, 0);
  waitvm0_barrier();
  int cur = 0;
  for (int kt = 0; kt < HID / 32; ++kt) {
    if (kt + 1 < HID / 32) { GEMM_STAGE(kt + 1, cur ^ 1); }
    const u16* Ac = As + cur * 4096;
    const u16* Bc = Bs + cur * 4096;
    bf16x8 af[4], bv[4];
#pragma unroll
    for (int m = 0; m < 4; ++m)
      af[m] = *reinterpret_cast<const bf16x8*>(Ac + (wr * 64 + m * 16 + lr) * 32 + lg * 8);
#pragma unroll
    for (int n = 0; n < 4; ++n)
      bv[n] = *reinterpret_cast<const bf16x8*>(Bc + (wc * 64 + n * 16 + lr) * 32 + lg * 8);
#pragma unroll
    for (int m = 0; m < 4; ++m)
#pragma unroll
      for (int n = 0; n < 4; ++n)
        acc[m][n] = __builtin_amdgcn_mfma_f32_16x16x32_bf16(af[m], bv[n], acc[m][n], 0, 0, 0);
    waitvm0_barrier();
    cur ^= 1;
  }
#undef GEMM_STAGE
}

// T1 bijective XCD remap (nwg % 8 == 0), by-fastest within an XCD chunk:
// A-panel (128 rows) stays L2-resident while B-panels stream.
DEVI void xcd_remap(int& bx, int& by) {
  int nx = gridDim.x, ny = gridDim.y;
  int nwg = nx * ny;
  int flat = blockIdx.y * nx + blockIdx.x;
  int w = (flat & 7) * (nwg >> 3) + (flat >> 3);
  bx = w / ny;
  by = w % ny;
}

// ---------- QKV projection + fused RoPE, scatter to [B,NH,S,HD] bf16 ----------
__global__ __launch_bounds__(256) void k_gemm_qkv(const u16* __restrict__ X, const u16* __restrict__ W,
                                                  u16* __restrict__ Qb, u16* __restrict__ Kb,
                                                  u16* __restrict__ Vb) {
  __shared__ __align__(16) u16 As[2 * 128 * 32];
  __shared__ __align__(16) u16 Bs[2 * 128 * 32];
  f32x4 acc[4][4] = {};
  int bx, by;
  xcd_remap(bx, by);
  const int brow = bx * 128, bcol = by * 128;
  gemm_ml(X, W, brow, bcol, As, Bs, acc);

  const int tid = threadIdx.x, wid = tid >> 6, lane = tid & 63;
  const int lr = lane & 15, lg = lane >> 4;
  const int wr = wid >> 1, wc = wid & 1;
  const int colbase = bcol + wc * 64;                 // wave covers exactly one head (64 cols, 64-aligned)
  const int mat = colbase >> 10;                      // 0=Q 1=K 2=V
  const int h = (colbase & 1023) >> 6;
  u16* dst = (mat == 0) ? Qb : ((mat == 1) ? Kb : Vb);
  // Q: fold 1/sqrt(64) AND log2(e) (softmax runs in exp2 domain)
  const float qsc = (mat == 0) ? 0.125f * 1.4426950408889634f : 1.0f;

  if (mat < 2) {
    const float L2B = 13.287712379549449f / 32.0f;    // log2(10000)/32
    const float inv0 = exp2f(-(float)lr * L2B);
    const float inv1 = exp2f(-(float)(16 + lr) * L2B);
#pragma unroll
    for (int m = 0; m < 4; ++m) {
#pragma unroll
      for (int r = 0; r < 4; ++r) {
        int grow = brow + wr * 64 + m * 16 + lg * 4 + r;
        int b = grow >> 11, s = grow & 2047;
        float s0, c0, s1, c1;
        __sincosf((float)s * inv0, &s0, &c0);
        __sincosf((float)s * inv1, &s1, &c1);
        float v0 = acc[m][0][r], v1 = acc[m][1][r], v2 = acc[m][2][r], v3 = acc[m][3][r];
        float r0 = (v0 * c0 - v2 * s0) * qsc;         // d<32: q*cos - q[d+32]*sin
        float r1 = (v1 * c1 - v3 * s1) * qsc;
        float r2 = (v2 * c0 + v0 * s0) * qsc;         // d>=32: q*cos + q[d-32]*sin
        float r3 = (v3 * c1 + v1 * s1) * qsc;
        size_t base = (((size_t)(b * NHEAD + h)) * S_LEN + s) * HDIM;
        dst[base + 0 * 16 + lr] = f2bf(r0);
        dst[base + 1 * 16 + lr] = f2bf(r1);
        dst[base + 2 * 16 + lr] = f2bf(r2);
        dst[base + 3 * 16 + lr] = f2bf(r3);
      }
    }
  } else {
#pragma unroll
    for (int m = 0; m < 4; ++m)
#pragma unroll
      for (int r = 0; r < 4; ++r) {
        int grow = brow + wr * 64 + m * 16 + lg * 4 + r;
        int b = grow >> 11, s = grow & 2047;
        size_t base = (((size_t)(b * NHEAD + h)) * S_LEN + s) * HDIM;
#pragma unroll
        for (int n = 0; n < 4; ++n)
          dst[base + n * 16 + lr] = f2bf(acc[m][n][r]);
      }
  }
}

// ---------- V transpose: [B,NH,S,HD] -> [B,NH,HD,S] ----------
__global__ __launch_bounds__(256) void k_vt(const u16* __restrict__ Vb, u16* __restrict__ Vt) {
  __shared__ u16 t[64 * 65];
  const int st = blockIdx.x, bh = blockIdx.y;
  const int tid = threadIdx.x;
  const u16* src = Vb + ((size_t)bh * S_LEN + st * 64) * HDIM;
  u16* dst = Vt + (size_t)bh * HDIM * S_LEN + st * 64;
#pragma unroll
  for (int c = 0; c < 2; ++c) {
    int r = c * 32 + (tid >> 3), col = (tid & 7) * 8;
    bf16x8 v = *reinterpret_cast<const bf16x8*>(src + r * HDIM + col);
#pragma unroll
    for (int i = 0; i < 8; ++i) t[(col + i) * 65 + r] = (u16)v[i];
  }
  __syncthreads();
#pragma unroll
  for (int c = 0; c < 2; ++c) {
    int d = c * 32 + (tid >> 3), s0 = (tid & 7) * 8;
    bf16x8 v;
#pragma unroll
    for (int i = 0; i < 8; ++i) v[i] = (short)t[d * 65 + s0 + i];
    *reinterpret_cast<bf16x8*>(dst + (size_t)d * S_LEN + s0) = v;
  }
}

// ---------- flash attention, swapped-QK^T in-register softmax, 2-phase dbuf ----------
// 4 waves x 32 q-rows; KT=64. S^T = mfma(K_frag, Q_frag): lane holds 16 k-vals
// for q = nq*16 + (lane&15). One barrier/tile; K/V double-buffered; XCD-grouped heads.
__global__ __launch_bounds__(256) void k_attn(const u16* __restrict__ Qb, const u16* __restrict__ Kb,
                                              const u16* __restrict__ Vt, u16* __restrict__ Ob) {
  __shared__ __align__(16) u16 Klds[2 * 64 * 64];     // [buf][j][d] swizzled: byte ^= (j&7)<<4
  __shared__ __align__(16) u16 Vlds[2 * 64 * 64];     // [buf][d][j] swizzled: byte ^= (d&7)<<4
  __shared__ __align__(16) u16 Plds[4][32 * 64];      // per-wave [q32][k64] swizzled: byte ^= (q&7)<<4
  // XCD remap: 8 heads x 16 qt per XCD chunk -> K/V working set ~4MB = one L2
  const int flat = blockIdx.y * 16 + blockIdx.x;
  const int xcd = flat & 7, idx = flat >> 3;
  const int bh = (xcd << 3) | (idx >> 4);
  const int qt = idx & 15;
  const int tid = threadIdx.x, wid = tid >> 6, lane = tid & 63;
  const int lr = lane & 15, lg = lane >> 4;
  const u16* Qp = Qb + (size_t)bh * S_LEN * HDIM;
  const u16* Kp = Kb + (size_t)bh * S_LEN * HDIM;
  const u16* Vp = Vt + (size_t)bh * HDIM * S_LEN;     // [d][s]

  // Q fragments (B-operand role): rows qt*128 + wid*32 + nq*16 + lr
  bf16x8 qf[2][2];
#pragma unroll
  for (int nq = 0; nq < 2; ++nq)
#pragma unroll
    for (int kk = 0; kk < 2; ++kk) {
      int s = qt * 128 + wid * 32 + nq * 16 + lr;
      qf[nq][kk] = *reinterpret_cast<const bf16x8*>(Qp + (size_t)s * HDIM + kk * 32 + lg * 8);
    }

  f32x4 o[2][4] = {};
  float mrun[2] = { -INFINITY, -INFINITY };
  float lrun[2] = { 0.f, 0.f };

#define ATTN_STAGE(KV0, BUF)                                                             \
  _Pragma("unroll")                                                                      \
  for (int c = 0; c < 2; ++c) {                                                          \
    int ob = c * 4096 + tid * 16;                                                        \
    int row = ob >> 7;                                                                   \
    int srcb = ob ^ ((row & 7) << 4);                                                    \
    int colel = (srcb & 127) >> 1;                                                       \
    gload16(Kp + (size_t)((KV0) + row) * HDIM + colel,                                   \
            (u16*)((char*)Klds + (BUF) * 8192 + c * 4096 + wid * 1024));                 \
    gload16(Vp + (size_t)row * S_LEN + (KV0) + colel,                                    \
            (u16*)((char*)Vlds + (BUF) * 8192 + c * 4096 + wid * 1024));                 \
  }

  ATTN_STAGE(0, 0);
  waitvm0_barrier();
  int cur = 0;

  for (int kv0 = 0; kv0 < S_LEN; kv0 += 64) {
    if (kv0 + 64 < S_LEN) { ATTN_STAGE(kv0 + 64, cur ^ 1); }
    const char* Kc = (char*)Klds + cur * 8192;
    const char* Vc = (char*)Vlds + cur * 8192;

    // --- S^T = K Q^T (Q pre-scaled by log2e/8): st[mk][nq], lane = (k=mk*16+lg*4+r, q=nq*16+lr)
    f32x4 st[4][2] = {};
#pragma unroll
    for (int kk = 0; kk < 2; ++kk) {
      bf16x8 bk[4];
#pragma unroll
      for (int n = 0; n < 4; ++n) {
        int row = n * 16 + lr;
        int byteoff = (row * 128 + kk * 64 + lg * 16) ^ ((row & 7) << 4);
        bk[n] = *reinterpret_cast<const bf16x8*>(Kc + byteoff);
      }
#pragma unroll
      for (int mk = 0; mk < 4; ++mk)
#pragma unroll
        for (int nq = 0; nq < 2; ++nq)
          st[mk][nq] = __builtin_amdgcn_mfma_f32_16x16x32_bf16(bk[mk], qf[nq][kk], st[mk][nq], 0, 0, 0);
    }

    // --- tile max per q-row (15 local fmax + 2 shfl) ---
    float tm[2];
#pragma unroll
    for (int nq = 0; nq < 2; ++nq) {
      float t0 = fmaxf(fmaxf(st[0][nq][0], st[0][nq][1]), fmaxf(st[0][nq][2], st[0][nq][3]));
      float t1 = fmaxf(fmaxf(st[1][nq][0], st[1][nq][1]), fmaxf(st[1][nq][2], st[1][nq][3]));
      float t2 = fmaxf(fmaxf(st[2][nq][0], st[2][nq][1]), fmaxf(st[2][nq][2], st[2][nq][3]));
      float t3 = fmaxf(fmaxf(st[3][nq][0], st[3][nq][1]), fmaxf(st[3][nq][2], st[3][nq][3]));
      float t = fmaxf(fmaxf(t0, t1), fmaxf(t2, t3));
      t = fmaxf(t, __shfl_xor(t, 16));
      t = fmaxf(t, __shfl_xor(t, 32));
      tm[nq] = t;
    }

    // --- defer-max (THR=8 in log2 domain: P <= 2^8) ---
    if (__any((tm[0] > mrun[0] + 8.f) || (tm[1] > mrun[1] + 8.f))) {
      float al[2];
#pragma unroll
      for (int nq = 0; nq < 2; ++nq) {
        float mn = fmaxf(mrun[nq], tm[nq]);
        al[nq] = __builtin_amdgcn_exp2f(mrun[nq] - mn);
        mrun[nq] = mn;
        lrun[nq] *= al[nq];
      }
#pragma unroll
      for (int m = 0; m < 2; ++m)
#pragma unroll
        for (int r = 0; r < 4; ++r) {
          float alv = __shfl(al[m], lg * 4 + r);      // o-row q=m*16+lg*4+r's factor lives at lane lg*4+r
#pragma unroll
          for (int n = 0; n < 4; ++n) o[m][n][r] *= alv;
        }
    }

    // --- P = exp2(S - m), row sum (15 local + 2 shfl) ---
#pragma unroll
    for (int mk = 0; mk < 4; ++mk)
#pragma unroll
      for (int nq = 0; nq < 2; ++nq)
#pragma unroll
        for (int r = 0; r < 4; ++r)
          st[mk][nq][r] = __builtin_amdgcn_exp2f(st[mk][nq][r] - mrun[nq]);
#pragma unroll
    for (int nq = 0; nq < 2; ++nq) {
      float s0 = (st[0][nq][0] + st[0][nq][1]) + (st[0][nq][2] + st[0][nq][3]);
      float s1 = (st[1][nq][0] + st[1][nq][1]) + (st[1][nq][2] + st[1][nq][3]);
      float s2 = (st[2][nq][0] + st[2][nq][1]) + (st[2][nq][2] + st[2][nq][3]);
      float s3 = (st[3][nq][0] + st[3][nq][1]) + (st[3][nq][2] + st[3][nq][3]);
      float rs = (s0 + s1) + (s2 + s3);
      rs += __shfl_xor(rs, 16);
      rs += __shfl_xor(rs, 32);
      lrun[nq] += rs;
    }

    // --- P^T(regs) -> P-layout LDS via cvt_pk pairs (k and k+1 contiguous: k=mk*16+lg*4+r)
    char* Pw = (char*)Plds[wid];
    {
      const int sw = (lr & 7) << 4;
#pragma unroll
      for (int nq = 0; nq < 2; ++nq) {
        int rowb = (nq * 16 + lr) * 128;
#pragma unroll
        for (int mk = 0; mk < 4; ++mk)
#pragma unroll
          for (int rp = 0; rp < 4; rp += 2) {
            int k = mk * 16 + lg * 4 + rp;
            uint32_t pk;
            asm("v_cvt_pk_bf16_f32 %0, %1, %2" : "=v"(pk) : "v"(st[mk][nq][rp]), "v"(st[mk][nq][rp + 1]));
            *(uint32_t*)(Pw + ((rowb + k * 2) ^ sw)) = pk;
          }
      }
    }
    asm volatile("s_waitcnt lgkmcnt(0)" ::: "memory");  // wave-private LDS: in-order DS + fence
    __builtin_amdgcn_sched_barrier(0);                  // rule #18: pin MFMA/ds_read below the wait

    // --- O += P V ---
#pragma unroll
    for (int kk = 0; kk < 2; ++kk) {
      bf16x8 pa[2], bv[4];
#pragma unroll
      for (int m = 0; m < 2; ++m) {
        int rowl = m * 16 + lr;
        int byteoff = (rowl * 128 + kk * 64 + lg * 16) ^ ((rowl & 7) << 4);
        pa[m] = *reinterpret_cast<const bf16x8*>(Pw + byteoff);
      }
#pragma unroll
      for (int n = 0; n < 4; ++n) {
        int d = n * 16 + lr;
        int byteoff = (d * 128 + kk * 64 + lg * 16) ^ ((d & 7) << 4);
        bv[n] = *reinterpret_cast<const bf16x8*>(Vc + byteoff);
      }
#pragma unroll
      for (int m = 0; m < 2; ++m)
#pragma unroll
        for (int n = 0; n < 4; ++n)
          o[m][n] = __builtin_amdgcn_mfma_f32_16x16x32_bf16(pa[m], bv[n], o[m][n], 0, 0, 0);
    }

    waitvm0_barrier();                                  // next tile staged; safe to swap
    cur ^= 1;
  }
#undef ATTN_STAGE

  // epilogue: fetch row-sums (lane lg*4+r holds q-row's lrun), normalize, store
  const int b = bh >> 4, h = bh & 15;
#pragma unroll
  for (int m = 0; m < 2; ++m)
#pragma unroll
    for (int r = 0; r < 4; ++r) {
      float lv = __shfl(lrun[m], lg * 4 + r);
      float inv = 1.0f / lv;
      int s = qt * 128 + wid * 32 + m * 16 + lg * 4 + r;
#pragma unroll
      for (int n = 0; n < 4; ++n) {
        int d = n * 16 + lr;
        Ob[(((size_t)b * S_LEN + s) * NHEAD + h) * HDIM + d] = f2bf(o[m][n][r] * inv);
      }
    }
}

// ---------- output projection -> fp32 d_out ----------
__global__ __launch_bounds__(256) void k_gemm_out(const u16* __restrict__ Aa, const u16* __restrict__ Wo,
                                                  float* __restrict__ out) {
  __shared__ __align__(16) u16 As[2 * 128 * 32];
  __shared__ __align__(16) u16 Bs[2 * 128 * 32];
  f32x4 acc[4][4] = {};
  int bx, by;
  xcd_remap(bx, by);
  const int brow = bx * 128, bcol = by * 128;
  gemm_ml(Aa, Wo, brow, bcol, As, Bs, acc);

  const int tid = threadIdx.x, wid = tid >> 6, lane = tid & 63;
  const int lr = lane & 15, lg = lane >> 4;
  const int wr = wid >> 1, wc = wid & 1;
#pragma unroll
  for (int m = 0; m < 4; ++m)
#pragma unroll
    for (int n = 0; n < 4; ++n)
#pragma unroll
      for (int r = 0; r < 4; ++r) {
        int grow = brow + wr * 64 + m * 16 + lg * 4 + r;
        int gcol = bcol + wc * 64 + n * 16 + lr;
        out[(size_t)grow * HID + gcol] = acc[m][n][r];
      }
}

// ---------- launcher ----------
extern "C" void kernel_launch(void* const* d_in, const int* in_sizes, int n_in,
                              void* d_out, int out_size, void* d_ws, size_t ws_size,
                              hipStream_t stream) {
  const float* hs = (const float*)d_in[0];
  const float* Wq = (const float*)d_in[1];
  const float* Wk = (const float*)d_in[2];
  const float* Wv = (const float*)d_in[3];
  const float* Wo = (const float*)d_in[4];

  char* ws = (char*)d_ws;
  u16* Xbf  = (u16*)(ws);                                   // 8192x1024      (16 MB)
  u16* Wqkv = (u16*)(ws + 16777216);                        // 3072x1024      ( 6 MB)
  u16* Wobf = (u16*)(ws + 23068672);                        // 1024x1024      ( 2 MB)
  u16* Qb   = (u16*)(ws + 25165824);                        // [B,NH,S,HD]    (16 MB)
  u16* Kb   = (u16*)(ws + 41943040);                        // [B,NH,S,HD]    (16 MB)
  u16* Vb   = (u16*)(ws + 58720256);                        // [B,NH,S,HD]    (16 MB)
  u16* AO   = (u16*)(ws + 75497472);                        // [B,S,NH,HD]    (16 MB) -> total 92274688 B
  u16* Vt   = Xbf;                                          // [B,NH,HD,S]: reuse Xbf (dead after k_gemm_qkv)

  k_cvt<<<2048, 256, 0, stream>>>(hs, Xbf, (MROWS * HID) / 4);
  k_cvtw<<<4096, 256, 0, stream>>>(Wq, Wk, Wv, Wo, Wqkv, Wobf);

  k_gemm_qkv<<<dim3(MROWS / 128, 3072 / 128), 256, 0, stream>>>(Xbf, Wqkv, Qb, Kb, Vb);
  k_vt<<<dim3(S_LEN / 64, 4 * NHEAD), 256, 0, stream>>>(Vb, Vt);
  k_attn<<<dim3(S_LEN / 128, 4 * NHEAD), 256, 0, stream>>>(Qb, Kb, Vt, AO);
  k_gemm_out<<<dim3(MROWS / 128, HID / 128), 256, 0, stream>>>(AO, Wobf, (float*)d_out);
}

// Round 7
// 240.715 us; speedup vs baseline: 1.0590x; 1.0590x over previous
//
#include <hip/hip_runtime.h>
#include <hip/hip_bf16.h>
#include <stdint.h>
#include <cmath>

typedef unsigned short u16;
typedef __attribute__((ext_vector_type(8))) short bf16x8;   // 8 bf16 = 4 VGPRs (MFMA A/B frag)
typedef __attribute__((ext_vector_type(4))) float f32x4;    // 16x16 MFMA C/D frag
typedef __attribute__((ext_vector_type(16))) float f32x16;  // 32x32 MFMA C/D frag

#define DEVI static __device__ __forceinline__

constexpr int S_LEN = 2048;
constexpr int NHEAD = 16;
constexpr int HDIM  = 64;
constexpr int HID   = 1024;
constexpr int MROWS = 4 * 2048;   // B*S = 8192

// ---------- helpers ----------
DEVI u16 f2bf(float x) {                       // RNE fp32 -> bf16
  union { float f; uint32_t u; } a; a.f = x;
  uint32_t r = a.u + 0x7fffu + ((a.u >> 16) & 1u);
  return (u16)(r >> 16);
}

DEVI void gload16(const void* g, void* l) {    // 16B global -> LDS direct (wave-uniform lds base + lane*16)
  __builtin_amdgcn_global_load_lds((const __attribute__((address_space(1))) void*)g,
                                   (__attribute__((address_space(3))) void*)l, 16, 0, 0);
}

DEVI void waitvm0_barrier() {                  // 2-phase tile boundary: drain own VMEM, raw barrier
  asm volatile("s_waitcnt vmcnt(0)" ::: "memory");
  __builtin_amdgcn_s_barrier();
}

// lane l <-> l^32 exchange via ds_bpermute (__shfl_xor) — semantics proven in
// R0-R4 passing kernels. (v_permlane32_swap_b32 asm was the R5/R6 suspect.)
DEVI float xchg_max(float x) { return fmaxf(x, __shfl_xor(x, 32)); }
DEVI float xchg_add(float x) { return x + __shfl_xor(x, 32); }

DEVI uint32_t cvtpk(float lo, float hi) {      // 2xf32 -> packed 2xbf16 (RNE)
  uint32_t r;
  asm("v_cvt_pk_bf16_f32 %0, %1, %2" : "=v"(r) : "v"(lo), "v"(hi));
  return r;
}

// ---------- fp32 -> bf16 convert ----------
__global__ void k_cvt(const float* __restrict__ src, u16* __restrict__ dst, int n4) {
  int stride = gridDim.x * blockDim.x;
  for (int i = blockIdx.x * blockDim.x + threadIdx.x; i < n4; i += stride) {
    float4 v = reinterpret_cast<const float4*>(src)[i];
    ushort4 o;
    o.x = f2bf(v.x); o.y = f2bf(v.y); o.z = f2bf(v.z); o.w = f2bf(v.w);
    reinterpret_cast<ushort4*>(dst)[i] = o;
  }
}

// all four 1024x1024 weights in one launch: Wq,Wk,Wv -> Wqkv (concat), Wo -> Wobf
__global__ void k_cvtw(const float* __restrict__ Wq, const float* __restrict__ Wk,
                       const float* __restrict__ Wv, const float* __restrict__ Wo,
                       u16* __restrict__ Wqkv, u16* __restrict__ Wobf) {
  constexpr int Q4 = (HID * HID) / 4;                 // float4s per matrix
  int i = blockIdx.x * blockDim.x + threadIdx.x;      // grid exactly covers 4*Q4
  int mat = i >> 18, loc = i & (Q4 - 1);              // Q4 = 2^18
  const float* src = (mat == 0) ? Wq : (mat == 1) ? Wk : (mat == 2) ? Wv : Wo;
  u16* dst = (mat < 3) ? (Wqkv + mat * HID * HID) : Wobf;
  float4 v = reinterpret_cast<const float4*>(src)[loc];
  ushort4 o;
  o.x = f2bf(v.x); o.y = f2bf(v.y); o.z = f2bf(v.z); o.w = f2bf(v.w);
  reinterpret_cast<ushort4*>(dst)[loc] = o;
}

// ---------- shared 128x128 B^T GEMM mainloop, 2-phase double-buffered ----------
DEVI void gemm_ml(const u16* __restrict__ A, const u16* __restrict__ Bm,
                  int brow, int bcol, u16* As, u16* Bs, f32x4 acc[4][4]) {
  const int tid = threadIdx.x;
  const int wid = tid >> 6, lane = tid & 63;
  const int lr = lane & 15, lg = lane >> 4;
  const int wr = wid >> 1, wc = wid & 1;

#define GEMM_STAGE(KT, BUF)                                                              \
  _Pragma("unroll")                                                                      \
  for (int c = 0; c < 2; ++c) {                                                          \
    int e = c * 2048 + tid * 8;                                                          \
    int row = e >> 5, kk = e & 31;                                                       \
    gload16(A  + (size_t)(brow + row) * HID + (KT) * 32 + kk,                            \
            As + (BUF) * 4096 + c * 2048 + wid * 512);                                   \
    gload16(Bm + (size_t)(bcol + row) * HID + (KT) * 32 + kk,                            \
            Bs + (BUF) * 4096 + c * 2048 + wid * 512);                                   \
  }

  GEMM_STAGE(0, 0);
  waitvm0_barrier();
  int cur = 0;
  for (int kt = 0; kt < HID / 32; ++kt) {
    if (kt + 1 < HID / 32) { GEMM_STAGE(kt + 1, cur ^ 1); }
    const u16* Ac = As + cur * 4096;
    const u16* Bc = Bs + cur * 4096;
    bf16x8 af[4], bv[4];
#pragma unroll
    for (int m = 0; m < 4; ++m)
      af[m] = *reinterpret_cast<const bf16x8*>(Ac + (wr * 64 + m * 16 + lr) * 32 + lg * 8);
#pragma unroll
    for (int n = 0; n < 4; ++n)
      bv[n] = *reinterpret_cast<const bf16x8*>(Bc + (wc * 64 + n * 16 + lr) * 32 + lg * 8);
#pragma unroll
    for (int m = 0; m < 4; ++m)
#pragma unroll
      for (int n = 0; n < 4; ++n)
        acc[m][n] = __builtin_amdgcn_mfma_f32_16x16x32_bf16(af[m], bv[n], acc[m][n], 0, 0, 0);
    waitvm0_barrier();
    cur ^= 1;
  }
#undef GEMM_STAGE
}

// T1 bijective XCD remap (nwg % 8 == 0), by-fastest within an XCD chunk
DEVI void xcd_remap(int& bx, int& by) {
  int nx = gridDim.x, ny = gridDim.y;
  int nwg = nx * ny;
  int flat = blockIdx.y * nx + blockIdx.x;
  int w = (flat & 7) * (nwg >> 3) + (flat >> 3);
  bx = w / ny;
  by = w % ny;
}

// ---------- QKV projection + fused RoPE, scatter to [B,NH,S,HD] bf16 ----------
__global__ __launch_bounds__(256) void k_gemm_qkv(const u16* __restrict__ X, const u16* __restrict__ W,
                                                  u16* __restrict__ Qb, u16* __restrict__ Kb,
                                                  u16* __restrict__ Vb) {
  __shared__ __align__(16) u16 As[2 * 128 * 32];
  __shared__ __align__(16) u16 Bs[2 * 128 * 32];
  f32x4 acc[4][4] = {};
  int bx, by;
  xcd_remap(bx, by);
  const int brow = bx * 128, bcol = by * 128;
  gemm_ml(X, W, brow, bcol, As, Bs, acc);

  const int tid = threadIdx.x, wid = tid >> 6, lane = tid & 63;
  const int lr = lane & 15, lg = lane >> 4;
  const int wr = wid >> 1, wc = wid & 1;
  const int colbase = bcol + wc * 64;                 // wave covers exactly one head (64 cols, 64-aligned)
  const int mat = colbase >> 10;                      // 0=Q 1=K 2=V
  const int h = (colbase & 1023) >> 6;
  u16* dst = (mat == 0) ? Qb : ((mat == 1) ? Kb : Vb);
  // Q: fold 1/sqrt(64) AND log2(e) (softmax runs in exp2 domain)
  const float qsc = (mat == 0) ? 0.125f * 1.4426950408889634f : 1.0f;

  if (mat < 2) {
    const float L2B = 13.287712379549449f / 32.0f;    // log2(10000)/32
    const float inv0 = exp2f(-(float)lr * L2B);
    const float inv1 = exp2f(-(float)(16 + lr) * L2B);
#pragma unroll
    for (int m = 0; m < 4; ++m) {
#pragma unroll
      for (int r = 0; r < 4; ++r) {
        int grow = brow + wr * 64 + m * 16 + lg * 4 + r;
        int b = grow >> 11, s = grow & 2047;
        float s0, c0, s1, c1;
        __sincosf((float)s * inv0, &s0, &c0);
        __sincosf((float)s * inv1, &s1, &c1);
        float v0 = acc[m][0][r], v1 = acc[m][1][r], v2 = acc[m][2][r], v3 = acc[m][3][r];
        float r0 = (v0 * c0 - v2 * s0) * qsc;         // d<32: q*cos - q[d+32]*sin
        float r1 = (v1 * c1 - v3 * s1) * qsc;
        float r2 = (v2 * c0 + v0 * s0) * qsc;         // d>=32: q*cos + q[d-32]*sin
        float r3 = (v3 * c1 + v1 * s1) * qsc;
        size_t base = (((size_t)(b * NHEAD + h)) * S_LEN + s) * HDIM;
        dst[base + 0 * 16 + lr] = f2bf(r0);
        dst[base + 1 * 16 + lr] = f2bf(r1);
        dst[base + 2 * 16 + lr] = f2bf(r2);
        dst[base + 3 * 16 + lr] = f2bf(r3);
      }
    }
  } else {
#pragma unroll
    for (int m = 0; m < 4; ++m)
#pragma unroll
      for (int r = 0; r < 4; ++r) {
        int grow = brow + wr * 64 + m * 16 + lg * 4 + r;
        int b = grow >> 11, s = grow & 2047;
        size_t base = (((size_t)(b * NHEAD + h)) * S_LEN + s) * HDIM;
#pragma unroll
        for (int n = 0; n < 4; ++n)
          dst[base + n * 16 + lr] = f2bf(acc[m][n][r]);
      }
  }
}

// ---------- V transpose: [B,NH,S,HD] -> [B,NH,HD,S] ----------
__global__ __launch_bounds__(256) void k_vt(const u16* __restrict__ Vb, u16* __restrict__ Vt) {
  __shared__ u16 t[64 * 65];
  const int st = blockIdx.x, bh = blockIdx.y;
  const int tid = threadIdx.x;
  const u16* src = Vb + ((size_t)bh * S_LEN + st * 64) * HDIM;
  u16* dst = Vt + (size_t)bh * HDIM * S_LEN + st * 64;
#pragma unroll
  for (int c = 0; c < 2; ++c) {
    int r = c * 32 + (tid >> 3), col = (tid & 7) * 8;
    bf16x8 v = *reinterpret_cast<const bf16x8*>(src + r * HDIM + col);
#pragma unroll
    for (int i = 0; i < 8; ++i) t[(col + i) * 65 + r] = (u16)v[i];
  }
  __syncthreads();
#pragma unroll
  for (int c = 0; c < 2; ++c) {
    int d = c * 32 + (tid >> 3), s0 = (tid & 7) * 8;
    bf16x8 v;
#pragma unroll
    for (int i = 0; i < 8; ++i) v[i] = (short)t[d * 65 + s0 + i];
    *reinterpret_cast<bf16x8*>(dst + (size_t)d * S_LEN + s0) = v;
  }
}

// ---------- flash attention: 32x32 MFMA, fully in-register softmax+P ----------
// 4 waves x 32 q-rows; KT=64. S^T = mfma32(K,Q^T): lane owns q=lane&31, k-slots
// interleaved with lane^32 per the C/D row map. PV consumes V in OWNERSHIP
// order (labeling-consistent for any slot map). Stats exchange via shfl_xor 32.
__global__ __launch_bounds__(256) void k_attn(const u16* __restrict__ Qb, const u16* __restrict__ Kb,
                                              const u16* __restrict__ Vt, u16* __restrict__ Ob) {
  __shared__ __align__(16) u16 Klds[2 * 64 * 64];     // [buf][k][d] swizzled: byte ^= (k&7)<<4
  __shared__ __align__(16) u16 Vlds[2 * 64 * 64];     // [buf][d][k] swizzled: byte ^= (d&7)<<4
  // XCD remap: 8 heads x 16 qt per XCD chunk -> K/V working set ~4MB = one L2
  const int flat = blockIdx.y * 16 + blockIdx.x;
  const int xcd = flat & 7, idx = flat >> 3;
  const int bh = (xcd << 3) | (idx >> 4);
  const int qt = idx & 15;
  const int tid = threadIdx.x, wid = tid >> 6, lane = tid & 63;
  const int l31 = lane & 31, lhi = lane >> 5;
  const u16* Qp = Qb + (size_t)bh * S_LEN * HDIM;
  const u16* Kp = Kb + (size_t)bh * S_LEN * HDIM;
  const u16* Vp = Vt + (size_t)bh * HDIM * S_LEN;     // [d][s]

  // Q fragments (B-operand): qf[dc][j] = Q[q=l31][dc*16 + lhi*8 + j], dc=0..3
  bf16x8 qf[4];
  {
    const int qrow = qt * 128 + wid * 32 + l31;
#pragma unroll
    for (int dc = 0; dc < 4; ++dc)
      qf[dc] = *reinterpret_cast<const bf16x8*>(Qp + (size_t)qrow * HDIM + dc * 16 + lhi * 8);
  }

  f32x16 o[2] = {};                                   // O[q][d]: col d = n*32+l31, row q = (r&3)+8(r>>2)+4lhi
  float mrun = -INFINITY, lrun = 0.f;

#define ATTN_STAGE(KV0, BUF)                                                             \
  _Pragma("unroll")                                                                      \
  for (int c = 0; c < 2; ++c) {                                                          \
    int ob = c * 4096 + tid * 16;                                                        \
    int row = ob >> 7;                                                                   \
    int srcb = ob ^ ((row & 7) << 4);                                                    \
    int colel = (srcb & 127) >> 1;                                                       \
    gload16(Kp + (size_t)((KV0) + row) * HDIM + colel,                                   \
            (u16*)((char*)Klds + (BUF) * 8192 + c * 4096 + wid * 1024));                 \
    gload16(Vp + (size_t)row * S_LEN + (KV0) + colel,                                    \
            (u16*)((char*)Vlds + (BUF) * 8192 + c * 4096 + wid * 1024));                 \
  }

  ATTN_STAGE(0, 0);
  waitvm0_barrier();
  int cur = 0;

  for (int kv0 = 0; kv0 < S_LEN; kv0 += 64) {
    if (kv0 + 64 < S_LEN) { ATTN_STAGE(kv0 + 64, cur ^ 1); }
    const char* Kc = (char*)Klds + cur * 8192;
    const char* Vc = (char*)Vlds + cur * 8192;

    // --- S^T = K Q^T: st[t] covers k = t*32 + (reg&3)+8(reg>>2)+4lhi, q = l31 ---
    f32x16 st[2] = {};
#pragma unroll
    for (int dc = 0; dc < 4; ++dc) {
#pragma unroll
      for (int t = 0; t < 2; ++t) {
        int row = t * 32 + l31;                       // A-frag: K[row][dc*16 + lhi*8 + j]
        int byteoff = (row * 128 + dc * 32 + lhi * 16) ^ ((row & 7) << 4);
        bf16x8 bk = *reinterpret_cast<const bf16x8*>(Kc + byteoff);
        st[t] = __builtin_amdgcn_mfma_f32_32x32x16_bf16(bk, qf[dc], st[t], 0, 0, 0);
      }
    }

    // --- row max: 31 local fmax + lane^32 exchange ---
    float tm = st[0][0];
#pragma unroll
    for (int r = 1; r < 16; ++r) tm = fmaxf(tm, st[0][r]);
#pragma unroll
    for (int r = 0; r < 16; ++r) tm = fmaxf(tm, st[1][r]);
    tm = xchg_max(tm);

    // --- defer-max (THR=8 in log2 domain: P <= 2^8) ---
    if (__any(tm > mrun + 8.f)) {
      float mn = fmaxf(mrun, tm);
      float al = __builtin_amdgcn_exp2f(mrun - mn);
      mrun = mn;
      lrun *= al;
#pragma unroll
      for (int r = 0; r < 16; ++r) {                  // broadcast al[q] to o-row owners
        float alv = __shfl(al, (r & 3) + 8 * (r >> 2) + 4 * lhi);
        o[0][r] *= alv;
        o[1][r] *= alv;
      }
    }

    // --- P = exp2(S - m); row sum ---
#pragma unroll
    for (int t = 0; t < 2; ++t)
#pragma unroll
      for (int r = 0; r < 16; ++r)
        st[t][r] = __builtin_amdgcn_exp2f(st[t][r] - mrun);
    {
      float rs = st[0][0];
#pragma unroll
      for (int r = 1; r < 16; ++r) rs += st[0][r];
#pragma unroll
      for (int r = 0; r < 16; ++r) rs += st[1][r];
      lrun += xchg_add(rs);
    }

    // --- O += P V, ownership-order k-slots (no cross-lane P movement) ---
    // A-frag slot j of pa[kc=t*2+h2] = st[t][h2*8+j] (own); B-frag slot j reads
    // V_lds row g = t*32 + h2*16 + 4*lhi + (j&3) + 8*(j>>2), col d.
#pragma unroll
    for (int t = 0; t < 2; ++t)
#pragma unroll
      for (int h2 = 0; h2 < 2; ++h2) {
        union { uint32_t w[4]; bf16x8 v; } pu;
#pragma unroll
        for (int w = 0; w < 4; ++w)
          pu.w[w] = cvtpk(st[t][h2 * 8 + 2 * w], st[t][h2 * 8 + 2 * w + 1]);
#pragma unroll
        for (int n = 0; n < 2; ++n) {
          int d = n * 32 + l31;
          int X = d * 128 + t * 64 + h2 * 32 + lhi * 8;   // byte addr of k-run start
          int sw = (d & 7) << 4;
          union { uint64_t q[2]; bf16x8 v; } bu;
          bu.q[0] = *reinterpret_cast<const uint64_t*>(Vc + (X ^ sw));          // k-slots j=0..3
          bu.q[1] = *reinterpret_cast<const uint64_t*>(Vc + ((X | 16) ^ sw));   // k-slots j=4..7
          o[n] = __builtin_amdgcn_mfma_f32_32x32x16_bf16(pu.v, bu.v, o[n], 0, 0, 0);
        }
      }

    waitvm0_barrier();                                // next tile staged; safe to swap
    cur ^= 1;
  }
#undef ATTN_STAGE

  // epilogue: normalize (lrun owner = lane q), store [B,S,NH,HD] bf16
  const int b = bh >> 4, h = bh & 15;
  const float linv = 1.0f / lrun;
#pragma unroll
  for (int r = 0; r < 16; ++r) {
    int qr = (r & 3) + 8 * (r >> 2) + 4 * lhi;
    float lv = __shfl(linv, qr);
    int s = qt * 128 + wid * 32 + qr;
#pragma unroll
    for (int n = 0; n < 2; ++n) {
      int d = n * 32 + l31;
      Ob[(((size_t)b * S_LEN + s) * NHEAD + h) * HDIM + d] = f2bf(o[n][r] * lv);
    }
  }
}

// ---------- output projection -> fp32 d_out ----------
__global__ __launch_bounds__(256) void k_gemm_out(const u16* __restrict__ Aa, const u16* __restrict__ Wo,
                                                  float* __restrict__ out) {
  __shared__ __align__(16) u16 As[2 * 128 * 32];
  __shared__ __align__(16) u16 Bs[2 * 128 * 32];
  f32x4 acc[4][4] = {};
  int bx, by;
  xcd_remap(bx, by);
  const int brow = bx * 128, bcol = by * 128;
  gemm_ml(Aa, Wo, brow, bcol, As, Bs, acc);

  const int tid = threadIdx.x, wid = tid >> 6, lane = tid & 63;
  const int lr = lane & 15, lg = lane >> 4;
  const int wr = wid >> 1, wc = wid & 1;
#pragma unroll
  for (int m = 0; m < 4; ++m)
#pragma unroll
    for (int n = 0; n < 4; ++n)
#pragma unroll
      for (int r = 0; r < 4; ++r) {
        int grow = brow + wr * 64 + m * 16 + lg * 4 + r;
        int gcol = bcol + wc * 64 + n * 16 + lr;
        out[(size_t)grow * HID + gcol] = acc[m][n][r];
      }
}

// ---------- launcher ----------
extern "C" void kernel_launch(void* const* d_in, const int* in_sizes, int n_in,
                              void* d_out, int out_size, void* d_ws, size_t ws_size,
                              hipStream_t stream) {
  const float* hs = (const float*)d_in[0];
  const float* Wq = (const float*)d_in[1];
  const float* Wk = (const float*)d_in[2];
  const float* Wv = (const float*)d_in[3];
  const float* Wo = (const float*)d_in[4];

  char* ws = (char*)d_ws;
  u16* Xbf  = (u16*)(ws);                                   // 8192x1024      (16 MB)
  u16* Wqkv = (u16*)(ws + 16777216);                        // 3072x1024      ( 6 MB)
  u16* Wobf = (u16*)(ws + 23068672);                        // 1024x1024      ( 2 MB)
  u16* Qb   = (u16*)(ws + 25165824);                        // [B,NH,S,HD]    (16 MB)
  u16* Kb   = (u16*)(ws + 41943040);                        // [B,NH,S,HD]    (16 MB)
  u16* Vb   = (u16*)(ws + 58720256);                        // [B,NH,S,HD]    (16 MB)
  u16* AO   = (u16*)(ws + 75497472);                        // [B,S,NH,HD]    (16 MB) -> total 92274688 B
  u16* Vt   = Xbf;                                          // [B,NH,HD,S]: reuse Xbf (dead after k_gemm_qkv)

  k_cvt<<<2048, 256, 0, stream>>>(hs, Xbf, (MROWS * HID) / 4);
  k_cvtw<<<4096, 256, 0, stream>>>(Wq, Wk, Wv, Wo, Wqkv, Wobf);

  k_gemm_qkv<<<dim3(MROWS / 128, 3072 / 128), 256, 0, stream>>>(Xbf, Wqkv, Qb, Kb, Vb);
  k_vt<<<dim3(S_LEN / 64, 4 * NHEAD), 256, 0, stream>>>(Vb, Vt);
  k_attn<<<dim3(S_LEN / 128, 4 * NHEAD), 256, 0, stream>>>(Qb, Kb, Vt, AO);
  k_gemm_out<<<dim3(MROWS / 128, HID / 128), 256, 0, stream>>>(AO, Wobf, (float*)d_out);
}

// Round 8
// 222.481 us; speedup vs baseline: 1.1458x; 1.0820x over previous
//
#include <hip/hip_runtime.h>
#include <hip/hip_bf16.h>
#include <stdint.h>
#include <cmath>

typedef unsigned short u16;
typedef __attribute__((ext_vector_type(8))) short bf16x8;   // 8 bf16 = 4 VGPRs (MFMA A/B frag)
typedef __attribute__((ext_vector_type(4))) float f32x4;    // 16x16 MFMA C/D frag
typedef __attribute__((ext_vector_type(16))) float f32x16;  // 32x32 MFMA C/D frag

#define DEVI static __device__ __forceinline__

constexpr int S_LEN = 2048;
constexpr int NHEAD = 16;
constexpr int HDIM  = 64;
constexpr int HID   = 1024;
constexpr int MROWS = 4 * 2048;   // B*S = 8192

// ---------- helpers ----------
DEVI u16 f2bf(float x) {                       // RNE fp32 -> bf16
  union { float f; uint32_t u; } a; a.f = x;
  uint32_t r = a.u + 0x7fffu + ((a.u >> 16) & 1u);
  return (u16)(r >> 16);
}

DEVI void gload16(const void* g, void* l) {    // 16B global -> LDS direct (wave-uniform lds base + lane*16)
  __builtin_amdgcn_global_load_lds((const __attribute__((address_space(1))) void*)g,
                                   (__attribute__((address_space(3))) void*)l, 16, 0, 0);
}

DEVI void waitvm0_barrier() {                  // 2-phase tile boundary: drain own VMEM, raw barrier
  asm volatile("s_waitcnt vmcnt(0)" ::: "memory");
  __builtin_amdgcn_s_barrier();
}

// lane l <-> l^32 exchange via ds_bpermute (__shfl_xor) — semantics proven.
DEVI float xchg_max(float x) { return fmaxf(x, __shfl_xor(x, 32)); }
DEVI float xchg_add(float x) { return x + __shfl_xor(x, 32); }

DEVI uint32_t cvtpk(float lo, float hi) {      // 2xf32 -> packed 2xbf16 (RNE)
  uint32_t r;
  asm("v_cvt_pk_bf16_f32 %0, %1, %2" : "=v"(r) : "v"(lo), "v"(hi));
  return r;
}

// tree reductions over two f32x16 (fully unrolled -> compile-time indices)
DEVI float tmax2(const f32x16& x, const f32x16& y) {
  float m[16];
#pragma unroll
  for (int i = 0; i < 16; ++i) m[i] = fmaxf(x[i], y[i]);
#pragma unroll
  for (int s = 8; s > 0; s >>= 1)
#pragma unroll
    for (int i = 0; i < s; ++i) m[i] = fmaxf(m[i], m[i + s]);
  return m[0];
}
DEVI float tsum2(const f32x16& x, const f32x16& y) {
  float m[16];
#pragma unroll
  for (int i = 0; i < 16; ++i) m[i] = x[i] + y[i];
#pragma unroll
  for (int s = 8; s > 0; s >>= 1)
#pragma unroll
    for (int i = 0; i < s; ++i) m[i] = m[i] + m[i + s];
  return m[0];
}

// ---------- fp32 -> bf16 convert ----------
__global__ void k_cvt(const float* __restrict__ src, u16* __restrict__ dst, int n4) {
  int stride = gridDim.x * blockDim.x;
  for (int i = blockIdx.x * blockDim.x + threadIdx.x; i < n4; i += stride) {
    float4 v = reinterpret_cast<const float4*>(src)[i];
    ushort4 o;
    o.x = f2bf(v.x); o.y = f2bf(v.y); o.z = f2bf(v.z); o.w = f2bf(v.w);
    reinterpret_cast<ushort4*>(dst)[i] = o;
  }
}

// all four 1024x1024 weights in one launch: Wq,Wk,Wv -> Wqkv (concat), Wo -> Wobf
__global__ void k_cvtw(const float* __restrict__ Wq, const float* __restrict__ Wk,
                       const float* __restrict__ Wv, const float* __restrict__ Wo,
                       u16* __restrict__ Wqkv, u16* __restrict__ Wobf) {
  constexpr int Q4 = (HID * HID) / 4;                 // float4s per matrix
  int i = blockIdx.x * blockDim.x + threadIdx.x;      // grid exactly covers 4*Q4
  int mat = i >> 18, loc = i & (Q4 - 1);              // Q4 = 2^18
  const float* src = (mat == 0) ? Wq : (mat == 1) ? Wk : (mat == 2) ? Wv : Wo;
  u16* dst = (mat < 3) ? (Wqkv + mat * HID * HID) : Wobf;
  float4 v = reinterpret_cast<const float4*>(src)[loc];
  ushort4 o;
  o.x = f2bf(v.x); o.y = f2bf(v.y); o.z = f2bf(v.z); o.w = f2bf(v.w);
  reinterpret_cast<ushort4*>(dst)[loc] = o;
}

// ---------- shared 128x128 B^T GEMM mainloop, 2-phase double-buffered ----------
DEVI void gemm_ml(const u16* __restrict__ A, const u16* __restrict__ Bm,
                  int brow, int bcol, u16* As, u16* Bs, f32x4 acc[4][4]) {
  const int tid = threadIdx.x;
  const int wid = tid >> 6, lane = tid & 63;
  const int lr = lane & 15, lg = lane >> 4;
  const int wr = wid >> 1, wc = wid & 1;

#define GEMM_STAGE(KT, BUF)                                                              \
  _Pragma("unroll")                                                                      \
  for (int c = 0; c < 2; ++c) {                                                          \
    int e = c * 2048 + tid * 8;                                                          \
    int row = e >> 5, kk = e & 31;                                                       \
    gload16(A  + (size_t)(brow + row) * HID + (KT) * 32 + kk,                            \
            As + (BUF) * 4096 + c * 2048 + wid * 512);                                   \
    gload16(Bm + (size_t)(bcol + row) * HID + (KT) * 32 + kk,                            \
            Bs + (BUF) * 4096 + c * 2048 + wid * 512);                                   \
  }

  GEMM_STAGE(0, 0);
  waitvm0_barrier();
  int cur = 0;
  for (int kt = 0; kt < HID / 32; ++kt) {
    if (kt + 1 < HID / 32) { GEMM_STAGE(kt + 1, cur ^ 1); }
    const u16* Ac = As + cur * 4096;
    const u16* Bc = Bs + cur * 4096;
    bf16x8 af[4], bv[4];
#pragma unroll
    for (int m = 0; m < 4; ++m)
      af[m] = *reinterpret_cast<const bf16x8*>(Ac + (wr * 64 + m * 16 + lr) * 32 + lg * 8);
#pragma unroll
    for (int n = 0; n < 4; ++n)
      bv[n] = *reinterpret_cast<const bf16x8*>(Bc + (wc * 64 + n * 16 + lr) * 32 + lg * 8);
#pragma unroll
    for (int m = 0; m < 4; ++m)
#pragma unroll
      for (int n = 0; n < 4; ++n)
        acc[m][n] = __builtin_amdgcn_mfma_f32_16x16x32_bf16(af[m], bv[n], acc[m][n], 0, 0, 0);
    waitvm0_barrier();
    cur ^= 1;
  }
#undef GEMM_STAGE
}

// T1 bijective XCD remap (nwg % 8 == 0), by-fastest within an XCD chunk
DEVI void xcd_remap(int& bx, int& by) {
  int nx = gridDim.x, ny = gridDim.y;
  int nwg = nx * ny;
  int flat = blockIdx.y * nx + blockIdx.x;
  int w = (flat & 7) * (nwg >> 3) + (flat >> 3);
  bx = w / ny;
  by = w % ny;
}

// ---------- QKV projection + fused RoPE, scatter to [B,NH,S,HD] bf16 ----------
__global__ __launch_bounds__(256) void k_gemm_qkv(const u16* __restrict__ X, const u16* __restrict__ W,
                                                  u16* __restrict__ Qb, u16* __restrict__ Kb,
                                                  u16* __restrict__ Vb) {
  __shared__ __align__(16) u16 As[2 * 128 * 32];
  __shared__ __align__(16) u16 Bs[2 * 128 * 32];
  f32x4 acc[4][4] = {};
  int bx, by;
  xcd_remap(bx, by);
  const int brow = bx * 128, bcol = by * 128;
  gemm_ml(X, W, brow, bcol, As, Bs, acc);

  const int tid = threadIdx.x, wid = tid >> 6, lane = tid & 63;
  const int lr = lane & 15, lg = lane >> 4;
  const int wr = wid >> 1, wc = wid & 1;
  const int colbase = bcol + wc * 64;                 // wave covers exactly one head (64 cols, 64-aligned)
  const int mat = colbase >> 10;                      // 0=Q 1=K 2=V
  const int h = (colbase & 1023) >> 6;
  u16* dst = (mat == 0) ? Qb : ((mat == 1) ? Kb : Vb);
  // Q: fold 1/sqrt(64) AND log2(e) (softmax runs in exp2 domain)
  const float qsc = (mat == 0) ? 0.125f * 1.4426950408889634f : 1.0f;

  if (mat < 2) {
    const float L2B = 13.287712379549449f / 32.0f;    // log2(10000)/32
    const float inv0 = exp2f(-(float)lr * L2B);
    const float inv1 = exp2f(-(float)(16 + lr) * L2B);
#pragma unroll
    for (int m = 0; m < 4; ++m) {
#pragma unroll
      for (int r = 0; r < 4; ++r) {
        int grow = brow + wr * 64 + m * 16 + lg * 4 + r;
        int b = grow >> 11, s = grow & 2047;
        float s0, c0, s1, c1;
        __sincosf((float)s * inv0, &s0, &c0);
        __sincosf((float)s * inv1, &s1, &c1);
        float v0 = acc[m][0][r], v1 = acc[m][1][r], v2 = acc[m][2][r], v3 = acc[m][3][r];
        float r0 = (v0 * c0 - v2 * s0) * qsc;         // d<32: q*cos - q[d+32]*sin
        float r1 = (v1 * c1 - v3 * s1) * qsc;
        float r2 = (v2 * c0 + v0 * s0) * qsc;         // d>=32: q*cos + q[d-32]*sin
        float r3 = (v3 * c1 + v1 * s1) * qsc;
        size_t base = (((size_t)(b * NHEAD + h)) * S_LEN + s) * HDIM;
        dst[base + 0 * 16 + lr] = f2bf(r0);
        dst[base + 1 * 16 + lr] = f2bf(r1);
        dst[base + 2 * 16 + lr] = f2bf(r2);
        dst[base + 3 * 16 + lr] = f2bf(r3);
      }
    }
  } else {
#pragma unroll
    for (int m = 0; m < 4; ++m)
#pragma unroll
      for (int r = 0; r < 4; ++r) {
        int grow = brow + wr * 64 + m * 16 + lg * 4 + r;
        int b = grow >> 11, s = grow & 2047;
        size_t base = (((size_t)(b * NHEAD + h)) * S_LEN + s) * HDIM;
#pragma unroll
        for (int n = 0; n < 4; ++n)
          dst[base + n * 16 + lr] = f2bf(acc[m][n][r]);
      }
  }
}

// ---------- V transpose: [B,NH,S,HD] -> [B,NH,HD,S] ----------
__global__ __launch_bounds__(256) void k_vt(const u16* __restrict__ Vb, u16* __restrict__ Vt) {
  __shared__ u16 t[64 * 65];
  const int st = blockIdx.x, bh = blockIdx.y;
  const int tid = threadIdx.x;
  const u16* src = Vb + ((size_t)bh * S_LEN + st * 64) * HDIM;
  u16* dst = Vt + (size_t)bh * HDIM * S_LEN + st * 64;
#pragma unroll
  for (int c = 0; c < 2; ++c) {
    int r = c * 32 + (tid >> 3), col = (tid & 7) * 8;
    bf16x8 v = *reinterpret_cast<const bf16x8*>(src + r * HDIM + col);
#pragma unroll
    for (int i = 0; i < 8; ++i) t[(col + i) * 65 + r] = (u16)v[i];
  }
  __syncthreads();
#pragma unroll
  for (int c = 0; c < 2; ++c) {
    int d = c * 32 + (tid >> 3), s0 = (tid & 7) * 8;
    bf16x8 v;
#pragma unroll
    for (int i = 0; i < 8; ++i) v[i] = (short)t[d * 65 + s0 + i];
    *reinterpret_cast<bf16x8*>(dst + (size_t)d * S_LEN + s0) = v;
  }
}

// ---------- flash attention: 32x32 MFMA, 64 q-rows/wave, 2-wave blocks ----------
// Each wave owns TWO 32-row output tiles (u=0,1); bk and bv LDS reads are each
// done ONCE per tile and feed both u-halves -> LDS-read volume per unit work
// halves vs 1 tile/wave. Softmax fully in-register (R7-proven path).
__global__ __launch_bounds__(128, 2) void k_attn(const u16* __restrict__ Qb, const u16* __restrict__ Kb,
                                                 const u16* __restrict__ Vt, u16* __restrict__ Ob) {
  __shared__ __align__(16) u16 Klds[2 * 64 * 64];     // [buf][k][d] swizzled: byte ^= (k&7)<<4
  __shared__ __align__(16) u16 Vlds[2 * 64 * 64];     // [buf][d][k] swizzled: byte ^= (d&7)<<4
  // XCD remap: 8 heads x 16 qt per XCD chunk -> K/V working set ~4MB = one L2
  const int flat = blockIdx.y * 16 + blockIdx.x;
  const int xcd = flat & 7, idx = flat >> 3;
  const int bh = (xcd << 3) | (idx >> 4);
  const int qt = idx & 15;
  const int tid = threadIdx.x, wid = tid >> 6, lane = tid & 63;
  const int l31 = lane & 31, lhi = lane >> 5;
  const u16* Qp = Qb + (size_t)bh * S_LEN * HDIM;
  const u16* Kp = Kb + (size_t)bh * S_LEN * HDIM;
  const u16* Vp = Vt + (size_t)bh * HDIM * S_LEN;     // [d][s]

  // Q fragments (B-operand): qf[u][dc][j] = Q[q = qt*128 + wid*64 + u*32 + l31][dc*16 + lhi*8 + j]
  bf16x8 qf[2][4];
#pragma unroll
  for (int u = 0; u < 2; ++u) {
    const int qrow = qt * 128 + wid * 64 + u * 32 + l31;
#pragma unroll
    for (int dc = 0; dc < 4; ++dc)
      qf[u][dc] = *reinterpret_cast<const bf16x8*>(Qp + (size_t)qrow * HDIM + dc * 16 + lhi * 8);
  }

  f32x16 o[2][2] = {};                                // o[u][n]
  float mrun[2] = { -INFINITY, -INFINITY };
  float lrun[2] = { 0.f, 0.f };

#define ATTN_STAGE(KV0, BUF)                                                             \
  _Pragma("unroll")                                                                      \
  for (int c = 0; c < 4; ++c) {                                                          \
    int ob = c * 2048 + tid * 16;                                                        \
    int row = ob >> 7;                                                                   \
    int srcb = ob ^ ((row & 7) << 4);                                                    \
    int colel = (srcb & 127) >> 1;                                                       \
    gload16(Kp + (size_t)((KV0) + row) * HDIM + colel,                                   \
            (u16*)((char*)Klds + (BUF) * 8192 + c * 2048 + wid * 1024));                 \
    gload16(Vp + (size_t)row * S_LEN + (KV0) + colel,                                    \
            (u16*)((char*)Vlds + (BUF) * 8192 + c * 2048 + wid * 1024));                 \
  }

  ATTN_STAGE(0, 0);
  waitvm0_barrier();
  int cur = 0;

  for (int kv0 = 0; kv0 < S_LEN; kv0 += 64) {
    if (kv0 + 64 < S_LEN) { ATTN_STAGE(kv0 + 64, cur ^ 1); }
    const char* Kc = (char*)Klds + cur * 8192;
    const char* Vc = (char*)Vlds + cur * 8192;

    // --- S^T = K Q^T for BOTH u (bk read once, shared) ---
    f32x16 st[2][2] = {};                             // [u][t]
#pragma unroll
    for (int dc = 0; dc < 4; ++dc) {
#pragma unroll
      for (int t = 0; t < 2; ++t) {
        int row = t * 32 + l31;                       // A-frag: K[row][dc*16 + lhi*8 + j]
        int byteoff = (row * 128 + dc * 32 + lhi * 16) ^ ((row & 7) << 4);
        bf16x8 bk = *reinterpret_cast<const bf16x8*>(Kc + byteoff);
        st[0][t] = __builtin_amdgcn_mfma_f32_32x32x16_bf16(bk, qf[0][dc], st[0][t], 0, 0, 0);
        st[1][t] = __builtin_amdgcn_mfma_f32_32x32x16_bf16(bk, qf[1][dc], st[1][t], 0, 0, 0);
      }
    }

    // --- row max (tree) + lane^32 exchange, per u ---
    float tm[2];
#pragma unroll
    for (int u = 0; u < 2; ++u) tm[u] = xchg_max(tmax2(st[u][0], st[u][1]));

    // --- defer-max (THR=8 in log2 domain: P <= 2^8) ---
    if (__any((tm[0] > mrun[0] + 8.f) || (tm[1] > mrun[1] + 8.f))) {
#pragma unroll
      for (int u = 0; u < 2; ++u) {
        float mn = fmaxf(mrun[u], tm[u]);
        float al = __builtin_amdgcn_exp2f(mrun[u] - mn);
        mrun[u] = mn;
        lrun[u] *= al;
#pragma unroll
        for (int r = 0; r < 16; ++r) {                // broadcast al[q] to o-row owners
          float alv = __shfl(al, (r & 3) + 8 * (r >> 2) + 4 * lhi);
          o[u][0][r] *= alv;
          o[u][1][r] *= alv;
        }
      }
    }

    // --- P = exp2(S - m); row sum (tree), per u ---
#pragma unroll
    for (int u = 0; u < 2; ++u) {
#pragma unroll
      for (int t = 0; t < 2; ++t)
#pragma unroll
        for (int r = 0; r < 16; ++r)
          st[u][t][r] = __builtin_amdgcn_exp2f(st[u][t][r] - mrun[u]);
      lrun[u] += xchg_add(tsum2(st[u][0], st[u][1]));
    }

    // --- O += P V, ownership-order k-slots; bv read once, shared by both u ---
#pragma unroll
    for (int t = 0; t < 2; ++t)
#pragma unroll
      for (int h2 = 0; h2 < 2; ++h2) {
        union { uint32_t w[4]; bf16x8 v; } pu[2];
#pragma unroll
        for (int u = 0; u < 2; ++u)
#pragma unroll
          for (int w = 0; w < 4; ++w)
            pu[u].w[w] = cvtpk(st[u][t][h2 * 8 + 2 * w], st[u][t][h2 * 8 + 2 * w + 1]);
#pragma unroll
        for (int n = 0; n < 2; ++n) {
          int d = n * 32 + l31;
          int X = d * 128 + t * 64 + h2 * 32 + lhi * 8;   // byte addr of k-run start
          int sw = (d & 7) << 4;
          union { uint64_t q[2]; bf16x8 v; } bu;
          bu.q[0] = *reinterpret_cast<const uint64_t*>(Vc + (X ^ sw));          // k-slots j=0..3
          bu.q[1] = *reinterpret_cast<const uint64_t*>(Vc + ((X | 16) ^ sw));   // k-slots j=4..7
          o[0][n] = __builtin_amdgcn_mfma_f32_32x32x16_bf16(pu[0].v, bu.v, o[0][n], 0, 0, 0);
          o[1][n] = __builtin_amdgcn_mfma_f32_32x32x16_bf16(pu[1].v, bu.v, o[1][n], 0, 0, 0);
        }
      }

    waitvm0_barrier();                                // next tile staged; safe to swap
    cur ^= 1;
  }
#undef ATTN_STAGE

  // epilogue: normalize (lrun owner = lane q), store [B,S,NH,HD] bf16
  const int b = bh >> 4, h = bh & 15;
#pragma unroll
  for (int u = 0; u < 2; ++u) {
    const float linv = 1.0f / lrun[u];
#pragma unroll
    for (int r = 0; r < 16; ++r) {
      int qr = (r & 3) + 8 * (r >> 2) + 4 * lhi;
      float lv = __shfl(linv, qr);
      int s = qt * 128 + wid * 64 + u * 32 + qr;
#pragma unroll
      for (int n = 0; n < 2; ++n) {
        int d = n * 32 + l31;
        Ob[(((size_t)b * S_LEN + s) * NHEAD + h) * HDIM + d] = f2bf(o[u][n][r] * lv);
      }
    }
  }
}

// ---------- output projection -> fp32 d_out ----------
__global__ __launch_bounds__(256) void k_gemm_out(const u16* __restrict__ Aa, const u16* __restrict__ Wo,
                                                  float* __restrict__ out) {
  __shared__ __align__(16) u16 As[2 * 128 * 32];
  __shared__ __align__(16) u16 Bs[2 * 128 * 32];
  f32x4 acc[4][4] = {};
  int bx, by;
  xcd_remap(bx, by);
  const int brow = bx * 128, bcol = by * 128;
  gemm_ml(Aa, Wo, brow, bcol, As, Bs, acc);

  const int tid = threadIdx.x, wid = tid >> 6, lane = tid & 63;
  const int lr = lane & 15, lg = lane >> 4;
  const int wr = wid >> 1, wc = wid & 1;
#pragma unroll
  for (int m = 0; m < 4; ++m)
#pragma unroll
    for (int n = 0; n < 4; ++n)
#pragma unroll
      for (int r = 0; r < 4; ++r) {
        int grow = brow + wr * 64 + m * 16 + lg * 4 + r;
        int gcol = bcol + wc * 64 + n * 16 + lr;
        out[(size_t)grow * HID + gcol] = acc[m][n][r];
      }
}

// ---------- launcher ----------
extern "C" void kernel_launch(void* const* d_in, const int* in_sizes, int n_in,
                              void* d_out, int out_size, void* d_ws, size_t ws_size,
                              hipStream_t stream) {
  const float* hs = (const float*)d_in[0];
  const float* Wq = (const float*)d_in[1];
  const float* Wk = (const float*)d_in[2];
  const float* Wv = (const float*)d_in[3];
  const float* Wo = (const float*)d_in[4];

  char* ws = (char*)d_ws;
  u16* Xbf  = (u16*)(ws);                                   // 8192x1024      (16 MB)
  u16* Wqkv = (u16*)(ws + 16777216);                        // 3072x1024      ( 6 MB)
  u16* Wobf = (u16*)(ws + 23068672);                        // 1024x1024      ( 2 MB)
  u16* Qb   = (u16*)(ws + 25165824);                        // [B,NH,S,HD]    (16 MB)
  u16* Kb   = (u16*)(ws + 41943040);                        // [B,NH,S,HD]    (16 MB)
  u16* Vb   = (u16*)(ws + 58720256);                        // [B,NH,S,HD]    (16 MB)
  u16* AO   = (u16*)(ws + 75497472);                        // [B,S,NH,HD]    (16 MB) -> total 92274688 B
  u16* Vt   = Xbf;                                          // [B,NH,HD,S]: reuse Xbf (dead after k_gemm_qkv)

  k_cvt<<<2048, 256, 0, stream>>>(hs, Xbf, (MROWS * HID) / 4);
  k_cvtw<<<4096, 256, 0, stream>>>(Wq, Wk, Wv, Wo, Wqkv, Wobf);

  k_gemm_qkv<<<dim3(MROWS / 128, 3072 / 128), 256, 0, stream>>>(Xbf, Wqkv, Qb, Kb, Vb);
  k_vt<<<dim3(S_LEN / 64, 4 * NHEAD), 256, 0, stream>>>(Vb, Vt);
  k_attn<<<dim3(S_LEN / 128, 4 * NHEAD), 128, 0, stream>>>(Qb, Kb, Vt, AO);
  k_gemm_out<<<dim3(MROWS / 128, HID / 128), 256, 0, stream>>>(AO, Wobf, (float*)d_out);
}

// Round 9
// 218.091 us; speedup vs baseline: 1.1688x; 1.0201x over previous
//
#include <hip/hip_runtime.h>
#include <hip/hip_bf16.h>
#include <stdint.h>
#include <cmath>

typedef unsigned short u16;
typedef __attribute__((ext_vector_type(8))) short bf16x8;   // 8 bf16 = 4 VGPRs (MFMA A/B frag)
typedef __attribute__((ext_vector_type(4))) float f32x4;    // 16x16 MFMA C/D frag
typedef __attribute__((ext_vector_type(16))) float f32x16;  // 32x32 MFMA C/D frag

#define DEVI static __device__ __forceinline__

constexpr int S_LEN = 2048;
constexpr int NHEAD = 16;
constexpr int HDIM  = 64;
constexpr int HID   = 1024;
constexpr int MROWS = 4 * 2048;   // B*S = 8192

// ---------- helpers ----------
DEVI u16 f2bf(float x) {                       // RNE fp32 -> bf16
  union { float f; uint32_t u; } a; a.f = x;
  uint32_t r = a.u + 0x7fffu + ((a.u >> 16) & 1u);
  return (u16)(r >> 16);
}

DEVI void gload16(const void* g, void* l) {    // 16B global -> LDS direct (wave-uniform lds base + lane*16)
  __builtin_amdgcn_global_load_lds((const __attribute__((address_space(1))) void*)g,
                                   (__attribute__((address_space(3))) void*)l, 16, 0, 0);
}

DEVI void waitvm0_barrier() {                  // 2-phase tile boundary: drain own VMEM, raw barrier
  asm volatile("s_waitcnt vmcnt(0)" ::: "memory");
  __builtin_amdgcn_s_barrier();
}

// lane l <-> l^32 exchange via ds_bpermute (__shfl_xor) — semantics proven.
DEVI float xchg_max(float x) { return fmaxf(x, __shfl_xor(x, 32)); }
DEVI float xchg_add(float x) { return x + __shfl_xor(x, 32); }

DEVI uint32_t cvtpk(float lo, float hi) {      // 2xf32 -> packed 2xbf16 (RNE)
  uint32_t r;
  asm("v_cvt_pk_bf16_f32 %0, %1, %2" : "=v"(r) : "v"(lo), "v"(hi));
  return r;
}

// tree reductions over two f32x16 (fully unrolled -> compile-time indices)
DEVI float tmax2(const f32x16& x, const f32x16& y) {
  float m[16];
#pragma unroll
  for (int i = 0; i < 16; ++i) m[i] = fmaxf(x[i], y[i]);
#pragma unroll
  for (int s = 8; s > 0; s >>= 1)
#pragma unroll
    for (int i = 0; i < s; ++i) m[i] = fmaxf(m[i], m[i + s]);
  return m[0];
}
DEVI float tsum2(const f32x16& x, const f32x16& y) {
  float m[16];
#pragma unroll
  for (int i = 0; i < 16; ++i) m[i] = x[i] + y[i];
#pragma unroll
  for (int s = 8; s > 0; s >>= 1)
#pragma unroll
    for (int i = 0; i < s; ++i) m[i] = m[i] + m[i + s];
  return m[0];
}

// ---------- fp32 -> bf16 convert ----------
__global__ void k_cvt(const float* __restrict__ src, u16* __restrict__ dst, int n4) {
  int stride = gridDim.x * blockDim.x;
  for (int i = blockIdx.x * blockDim.x + threadIdx.x; i < n4; i += stride) {
    float4 v = reinterpret_cast<const float4*>(src)[i];
    ushort4 o;
    o.x = f2bf(v.x); o.y = f2bf(v.y); o.z = f2bf(v.z); o.w = f2bf(v.w);
    reinterpret_cast<ushort4*>(dst)[i] = o;
  }
}

// all four 1024x1024 weights in one launch: Wq,Wk,Wv -> Wqkv (concat), Wo -> Wobf
__global__ void k_cvtw(const float* __restrict__ Wq, const float* __restrict__ Wk,
                       const float* __restrict__ Wv, const float* __restrict__ Wo,
                       u16* __restrict__ Wqkv, u16* __restrict__ Wobf) {
  constexpr int Q4 = (HID * HID) / 4;                 // float4s per matrix
  int i = blockIdx.x * blockDim.x + threadIdx.x;      // grid exactly covers 4*Q4
  int mat = i >> 18, loc = i & (Q4 - 1);              // Q4 = 2^18
  const float* src = (mat == 0) ? Wq : (mat == 1) ? Wk : (mat == 2) ? Wv : Wo;
  u16* dst = (mat < 3) ? (Wqkv + mat * HID * HID) : Wobf;
  float4 v = reinterpret_cast<const float4*>(src)[loc];
  ushort4 o;
  o.x = f2bf(v.x); o.y = f2bf(v.y); o.z = f2bf(v.z); o.w = f2bf(v.w);
  reinterpret_cast<ushort4*>(dst)[loc] = o;
}

// ---------- shared 128x128 B^T GEMM mainloop, 2-phase double-buffered ----------
DEVI void gemm_ml(const u16* __restrict__ A, const u16* __restrict__ Bm,
                  int brow, int bcol, u16* As, u16* Bs, f32x4 acc[4][4]) {
  const int tid = threadIdx.x;
  const int wid = tid >> 6, lane = tid & 63;
  const int lr = lane & 15, lg = lane >> 4;
  const int wr = wid >> 1, wc = wid & 1;

#define GEMM_STAGE(KT, BUF)                                                              \
  _Pragma("unroll")                                                                      \
  for (int c = 0; c < 2; ++c) {                                                          \
    int e = c * 2048 + tid * 8;                                                          \
    int row = e >> 5, kk = e & 31;                                                       \
    gload16(A  + (size_t)(brow + row) * HID + (KT) * 32 + kk,                            \
            As + (BUF) * 4096 + c * 2048 + wid * 512);                                   \
    gload16(Bm + (size_t)(bcol + row) * HID + (KT) * 32 + kk,                            \
            Bs + (BUF) * 4096 + c * 2048 + wid * 512);                                   \
  }

  GEMM_STAGE(0, 0);
  waitvm0_barrier();
  int cur = 0;
  for (int kt = 0; kt < HID / 32; ++kt) {
    if (kt + 1 < HID / 32) { GEMM_STAGE(kt + 1, cur ^ 1); }
    const u16* Ac = As + cur * 4096;
    const u16* Bc = Bs + cur * 4096;
    bf16x8 af[4], bv[4];
#pragma unroll
    for (int m = 0; m < 4; ++m)
      af[m] = *reinterpret_cast<const bf16x8*>(Ac + (wr * 64 + m * 16 + lr) * 32 + lg * 8);
#pragma unroll
    for (int n = 0; n < 4; ++n)
      bv[n] = *reinterpret_cast<const bf16x8*>(Bc + (wc * 64 + n * 16 + lr) * 32 + lg * 8);
#pragma unroll
    for (int m = 0; m < 4; ++m)
#pragma unroll
      for (int n = 0; n < 4; ++n)
        acc[m][n] = __builtin_amdgcn_mfma_f32_16x16x32_bf16(af[m], bv[n], acc[m][n], 0, 0, 0);
    waitvm0_barrier();
    cur ^= 1;
  }
#undef GEMM_STAGE
}

// T1 bijective XCD remap (nwg % 8 == 0), by-fastest within an XCD chunk
DEVI void xcd_remap(int& bx, int& by) {
  int nx = gridDim.x, ny = gridDim.y;
  int nwg = nx * ny;
  int flat = blockIdx.y * nx + blockIdx.x;
  int w = (flat & 7) * (nwg >> 3) + (flat >> 3);
  bx = w / ny;
  by = w % ny;
}

// ---------- QKV projection + fused RoPE; Q/K scatter to [B,NH,S,HD], V stored
// TRANSPOSED directly to Vt [B,NH,HD,S] (8B packed stores; each (d,block) row
// segment is a full 128B L2 line -> HBM write efficiency preserved) ----------
__global__ __launch_bounds__(256) void k_gemm_qkv(const u16* __restrict__ X, const u16* __restrict__ W,
                                                  u16* __restrict__ Qb, u16* __restrict__ Kb,
                                                  u16* __restrict__ Vt) {
  __shared__ __align__(16) u16 As[2 * 128 * 32];
  __shared__ __align__(16) u16 Bs[2 * 128 * 32];
  f32x4 acc[4][4] = {};
  int bx, by;
  xcd_remap(bx, by);
  const int brow = bx * 128, bcol = by * 128;
  gemm_ml(X, W, brow, bcol, As, Bs, acc);

  const int tid = threadIdx.x, wid = tid >> 6, lane = tid & 63;
  const int lr = lane & 15, lg = lane >> 4;
  const int wr = wid >> 1, wc = wid & 1;
  const int colbase = bcol + wc * 64;                 // wave covers exactly one head (64 cols, 64-aligned)
  const int mat = colbase >> 10;                      // 0=Q 1=K 2=V
  const int h = (colbase & 1023) >> 6;
  // Q: fold 1/sqrt(64) AND log2(e) (softmax runs in exp2 domain)
  const float qsc = (mat == 0) ? 0.125f * 1.4426950408889634f : 1.0f;

  if (mat < 2) {
    u16* dst = (mat == 0) ? Qb : Kb;
    const float L2B = 13.287712379549449f / 32.0f;    // log2(10000)/32
    const float inv0 = exp2f(-(float)lr * L2B);
    const float inv1 = exp2f(-(float)(16 + lr) * L2B);
#pragma unroll
    for (int m = 0; m < 4; ++m) {
#pragma unroll
      for (int r = 0; r < 4; ++r) {
        int grow = brow + wr * 64 + m * 16 + lg * 4 + r;
        int b = grow >> 11, s = grow & 2047;
        float s0, c0, s1, c1;
        __sincosf((float)s * inv0, &s0, &c0);
        __sincosf((float)s * inv1, &s1, &c1);
        float v0 = acc[m][0][r], v1 = acc[m][1][r], v2 = acc[m][2][r], v3 = acc[m][3][r];
        float r0 = (v0 * c0 - v2 * s0) * qsc;         // d<32: q*cos - q[d+32]*sin
        float r1 = (v1 * c1 - v3 * s1) * qsc;
        float r2 = (v2 * c0 + v0 * s0) * qsc;         // d>=32: q*cos + q[d-32]*sin
        float r3 = (v3 * c1 + v1 * s1) * qsc;
        size_t base = (((size_t)(b * NHEAD + h)) * S_LEN + s) * HDIM;
        dst[base + 0 * 16 + lr] = f2bf(r0);
        dst[base + 1 * 16 + lr] = f2bf(r1);
        dst[base + 2 * 16 + lr] = f2bf(r2);
        dst[base + 3 * 16 + lr] = f2bf(r3);
      }
    }
  } else {
    // V: transposed store. Thread holds 4 consecutive s (r=0..3) for col d.
#pragma unroll
    for (int m = 0; m < 4; ++m) {
      int g0 = brow + wr * 64 + m * 16 + lg * 4;      // s of r=0 (4-aligned)
      int b = g0 >> 11, s0 = g0 & 2047;
#pragma unroll
      for (int n = 0; n < 4; ++n) {
        int d = n * 16 + lr;
        ushort4 o;
        o.x = f2bf(acc[m][n][0]); o.y = f2bf(acc[m][n][1]);
        o.z = f2bf(acc[m][n][2]); o.w = f2bf(acc[m][n][3]);
        *reinterpret_cast<ushort4*>(
            Vt + (((size_t)(b * NHEAD + h)) * HDIM + d) * S_LEN + s0) = o;
      }
    }
  }
}

// ---------- flash attention: 32x32 MFMA, 64 q-rows/wave, 2-wave blocks ----------
// bk/bv LDS reads each done ONCE per tile, shared by both u-halves. Softmax
// fully in-register. T5 setprio around MFMA clusters.
__global__ __launch_bounds__(128, 2) void k_attn(const u16* __restrict__ Qb, const u16* __restrict__ Kb,
                                                 const u16* __restrict__ Vt, u16* __restrict__ Ob) {
  __shared__ __align__(16) u16 Klds[2 * 64 * 64];     // [buf][k][d] swizzled: byte ^= (k&7)<<4
  __shared__ __align__(16) u16 Vlds[2 * 64 * 64];     // [buf][d][k] swizzled: byte ^= (d&7)<<4
  // XCD remap: 8 heads x 16 qt per XCD chunk -> K/V working set ~4MB = one L2
  const int flat = blockIdx.y * 16 + blockIdx.x;
  const int xcd = flat & 7, idx = flat >> 3;
  const int bh = (xcd << 3) | (idx >> 4);
  const int qt = idx & 15;
  const int tid = threadIdx.x, wid = tid >> 6, lane = tid & 63;
  const int l31 = lane & 31, lhi = lane >> 5;
  const u16* Qp = Qb + (size_t)bh * S_LEN * HDIM;
  const u16* Kp = Kb + (size_t)bh * S_LEN * HDIM;
  const u16* Vp = Vt + (size_t)bh * HDIM * S_LEN;     // [d][s]

  // Q fragments (B-operand): qf[u][dc][j] = Q[q = qt*128 + wid*64 + u*32 + l31][dc*16 + lhi*8 + j]
  bf16x8 qf[2][4];
#pragma unroll
  for (int u = 0; u < 2; ++u) {
    const int qrow = qt * 128 + wid * 64 + u * 32 + l31;
#pragma unroll
    for (int dc = 0; dc < 4; ++dc)
      qf[u][dc] = *reinterpret_cast<const bf16x8*>(Qp + (size_t)qrow * HDIM + dc * 16 + lhi * 8);
  }

  f32x16 o[2][2] = {};                                // o[u][n]
  float mrun[2] = { -INFINITY, -INFINITY };
  float lrun[2] = { 0.f, 0.f };

#define ATTN_STAGE(KV0, BUF)                                                             \
  _Pragma("unroll")                                                                      \
  for (int c = 0; c < 4; ++c) {                                                          \
    int ob = c * 2048 + tid * 16;                                                        \
    int row = ob >> 7;                                                                   \
    int srcb = ob ^ ((row & 7) << 4);                                                    \
    int colel = (srcb & 127) >> 1;                                                       \
    gload16(Kp + (size_t)((KV0) + row) * HDIM + colel,                                   \
            (u16*)((char*)Klds + (BUF) * 8192 + c * 2048 + wid * 1024));                 \
    gload16(Vp + (size_t)row * S_LEN + (KV0) + colel,                                    \
            (u16*)((char*)Vlds + (BUF) * 8192 + c * 2048 + wid * 1024));                 \
  }

  ATTN_STAGE(0, 0);
  waitvm0_barrier();
  int cur = 0;

  for (int kv0 = 0; kv0 < S_LEN; kv0 += 64) {
    if (kv0 + 64 < S_LEN) { ATTN_STAGE(kv0 + 64, cur ^ 1); }
    const char* Kc = (char*)Klds + cur * 8192;
    const char* Vc = (char*)Vlds + cur * 8192;

    // --- S^T = K Q^T for BOTH u (bk read once, shared) ---
    f32x16 st[2][2] = {};                             // [u][t]
    __builtin_amdgcn_s_setprio(1);
#pragma unroll
    for (int dc = 0; dc < 4; ++dc) {
#pragma unroll
      for (int t = 0; t < 2; ++t) {
        int row = t * 32 + l31;                       // A-frag: K[row][dc*16 + lhi*8 + j]
        int byteoff = (row * 128 + dc * 32 + lhi * 16) ^ ((row & 7) << 4);
        bf16x8 bk = *reinterpret_cast<const bf16x8*>(Kc + byteoff);
        st[0][t] = __builtin_amdgcn_mfma_f32_32x32x16_bf16(bk, qf[0][dc], st[0][t], 0, 0, 0);
        st[1][t] = __builtin_amdgcn_mfma_f32_32x32x16_bf16(bk, qf[1][dc], st[1][t], 0, 0, 0);
      }
    }
    __builtin_amdgcn_s_setprio(0);

    // --- row max (tree) + lane^32 exchange, per u ---
    float tm[2];
#pragma unroll
    for (int u = 0; u < 2; ++u) tm[u] = xchg_max(tmax2(st[u][0], st[u][1]));

    // --- defer-max (THR=8 in log2 domain: P <= 2^8) ---
    if (__any((tm[0] > mrun[0] + 8.f) || (tm[1] > mrun[1] + 8.f))) {
#pragma unroll
      for (int u = 0; u < 2; ++u) {
        float mn = fmaxf(mrun[u], tm[u]);
        float al = __builtin_amdgcn_exp2f(mrun[u] - mn);
        mrun[u] = mn;
        lrun[u] *= al;
#pragma unroll
        for (int r = 0; r < 16; ++r) {                // broadcast al[q] to o-row owners
          float alv = __shfl(al, (r & 3) + 8 * (r >> 2) + 4 * lhi);
          o[u][0][r] *= alv;
          o[u][1][r] *= alv;
        }
      }
    }

    // --- P = exp2(S - m); row sum (tree), per u ---
#pragma unroll
    for (int u = 0; u < 2; ++u) {
#pragma unroll
      for (int t = 0; t < 2; ++t)
#pragma unroll
        for (int r = 0; r < 16; ++r)
          st[u][t][r] = __builtin_amdgcn_exp2f(st[u][t][r] - mrun[u]);
      lrun[u] += xchg_add(tsum2(st[u][0], st[u][1]));
    }

    // --- O += P V, ownership-order k-slots; bv read once, shared by both u ---
    __builtin_amdgcn_s_setprio(1);
#pragma unroll
    for (int t = 0; t < 2; ++t)
#pragma unroll
      for (int h2 = 0; h2 < 2; ++h2) {
        union { uint32_t w[4]; bf16x8 v; } pu[2];
#pragma unroll
        for (int u = 0; u < 2; ++u)
#pragma unroll
          for (int w = 0; w < 4; ++w)
            pu[u].w[w] = cvtpk(st[u][t][h2 * 8 + 2 * w], st[u][t][h2 * 8 + 2 * w + 1]);
#pragma unroll
        for (int n = 0; n < 2; ++n) {
          int d = n * 32 + l31;
          int X = d * 128 + t * 64 + h2 * 32 + lhi * 8;   // byte addr of k-run start
          int sw = (d & 7) << 4;
          union { uint64_t q[2]; bf16x8 v; } bu;
          bu.q[0] = *reinterpret_cast<const uint64_t*>(Vc + (X ^ sw));          // k-slots j=0..3
          bu.q[1] = *reinterpret_cast<const uint64_t*>(Vc + ((X | 16) ^ sw));   // k-slots j=4..7
          o[0][n] = __builtin_amdgcn_mfma_f32_32x32x16_bf16(pu[0].v, bu.v, o[0][n], 0, 0, 0);
          o[1][n] = __builtin_amdgcn_mfma_f32_32x32x16_bf16(pu[1].v, bu.v, o[1][n], 0, 0, 0);
        }
      }
    __builtin_amdgcn_s_setprio(0);

    waitvm0_barrier();                                // next tile staged; safe to swap
    cur ^= 1;
  }
#undef ATTN_STAGE

  // epilogue: normalize (lrun owner = lane q), store [B,S,NH,HD] bf16
  const int b = bh >> 4, h = bh & 15;
#pragma unroll
  for (int u = 0; u < 2; ++u) {
    const float linv = 1.0f / lrun[u];
#pragma unroll
    for (int r = 0; r < 16; ++r) {
      int qr = (r & 3) + 8 * (r >> 2) + 4 * lhi;
      float lv = __shfl(linv, qr);
      int s = qt * 128 + wid * 64 + u * 32 + qr;
#pragma unroll
      for (int n = 0; n < 2; ++n) {
        int d = n * 32 + l31;
        Ob[(((size_t)b * S_LEN + s) * NHEAD + h) * HDIM + d] = f2bf(o[u][n][r] * lv);
      }
    }
  }
}

// ---------- output projection -> fp32 d_out ----------
__global__ __launch_bounds__(256) void k_gemm_out(const u16* __restrict__ Aa, const u16* __restrict__ Wo,
                                                  float* __restrict__ out) {
  __shared__ __align__(16) u16 As[2 * 128 * 32];
  __shared__ __align__(16) u16 Bs[2 * 128 * 32];
  f32x4 acc[4][4] = {};
  int bx, by;
  xcd_remap(bx, by);
  const int brow = bx * 128, bcol = by * 128;
  gemm_ml(Aa, Wo, brow, bcol, As, Bs, acc);

  const int tid = threadIdx.x, wid = tid >> 6, lane = tid & 63;
  const int lr = lane & 15, lg = lane >> 4;
  const int wr = wid >> 1, wc = wid & 1;
#pragma unroll
  for (int m = 0; m < 4; ++m)
#pragma unroll
    for (int n = 0; n < 4; ++n)
#pragma unroll
      for (int r = 0; r < 4; ++r) {
        int grow = brow + wr * 64 + m * 16 + lg * 4 + r;
        int gcol = bcol + wc * 64 + n * 16 + lr;
        out[(size_t)grow * HID + gcol] = acc[m][n][r];
      }
}

// ---------- launcher ----------
extern "C" void kernel_launch(void* const* d_in, const int* in_sizes, int n_in,
                              void* d_out, int out_size, void* d_ws, size_t ws_size,
                              hipStream_t stream) {
  const float* hs = (const float*)d_in[0];
  const float* Wq = (const float*)d_in[1];
  const float* Wk = (const float*)d_in[2];
  const float* Wv = (const float*)d_in[3];
  const float* Wo = (const float*)d_in[4];

  char* ws = (char*)d_ws;
  u16* Xbf  = (u16*)(ws);                                   // 8192x1024      (16 MB)
  u16* Wqkv = (u16*)(ws + 16777216);                        // 3072x1024      ( 6 MB)
  u16* Wobf = (u16*)(ws + 23068672);                        // 1024x1024      ( 2 MB)
  u16* Qb   = (u16*)(ws + 25165824);                        // [B,NH,S,HD]    (16 MB)
  u16* Kb   = (u16*)(ws + 41943040);                        // [B,NH,S,HD]    (16 MB)
  u16* Vt   = (u16*)(ws + 58720256);                        // [B,NH,HD,S]    (16 MB) - written transposed
  u16* AO   = (u16*)(ws + 75497472);                        // [B,S,NH,HD]    (16 MB) -> total 92274688 B

  k_cvt<<<2048, 256, 0, stream>>>(hs, Xbf, (MROWS * HID) / 4);
  k_cvtw<<<4096, 256, 0, stream>>>(Wq, Wk, Wv, Wo, Wqkv, Wobf);

  k_gemm_qkv<<<dim3(MROWS / 128, 3072 / 128), 256, 0, stream>>>(Xbf, Wqkv, Qb, Kb, Vt);
  k_attn<<<dim3(S_LEN / 128, 4 * NHEAD), 128, 0, stream>>>(Qb, Kb, Vt, AO);
  k_gemm_out<<<dim3(MROWS / 128, HID / 128), 256, 0, stream>>>(AO, Wobf, (float*)d_out);
}